// Round 3
// baseline (390.105 us; speedup 1.0000x reference)
//
#include <hip/hip_runtime.h>
#include <hip/hip_bf16.h>

// Problem: B=4,S=4096 tokens (16384), HIDDEN=1024, 16 heads x 64 dim.
// "Attention" mixes HEADS per token (16x16 softmax over heads), not sequence.
//
// DTYPE (R2 finding): inputs and output are FP32 per the reference
// (jnp.float32); the test merely relaxes the threshold to a bf16 floor
// (floor_eps_k=8, thr=4.5e-2). R1/R2 NaN came from casting fp32 buffers to
// bf16* (random low-half bits -> ~0.4% NaN/Inf -> GEMM -> all-NaN).
// Compute stays bf16-MFMA with fp32 accumulate; conversion happens in the
// GEMM staging step.
//
// Pipeline:
//   q = X @ Wq^T ; k = X @ Wk^T ; v = X @ Wv^T   (gemm_bt<float,float,bf16>)
//   per token: S=QK^T/8, P=softmax(S), O=PV      (attn, bf16, O in-place)
//   out = O @ Wo^T                               (gemm_bt<bf16,float,float>)
// Workspace: q,k,v bf16 = 3 * 16384*1024*2B = 100.7 MB.

typedef __bf16 bf16;
typedef __attribute__((ext_vector_type(8))) __bf16 bf16x8;
typedef __attribute__((ext_vector_type(4))) float floatx4;

#define HIDDEN 1024
#define BM 128
#define BN 128
#define BK 32

// Load 8 contiguous elements as bf16x8 (converting if source is fp32).
__device__ __forceinline__ bf16x8 load8(const bf16* p) {
    return *(const bf16x8*)p;
}
__device__ __forceinline__ bf16x8 load8(const float* p) {
    floatx4 lo = *(const floatx4*)p;
    floatx4 hi = *(const floatx4*)(p + 4);
    bf16x8 r;
#pragma unroll
    for (int i = 0; i < 4; ++i) { r[i] = (bf16)lo[i]; r[i + 4] = (bf16)hi[i]; }
    return r;
}

// C[m,n] = sum_k A[m,k] * W[n,k]   (A: MxK row-major, W: NxK row-major)
// Block: 256 threads = 4 waves (2x2), tile 128x128, BK=32. bf16 MFMA,
// fp32 accumulate; staging converts to bf16 en route to LDS.
template <typename TA, typename TB, typename TC>
__global__ __launch_bounds__(256, 2) void gemm_bt(
    const TA* __restrict__ A, const TB* __restrict__ W,
    TC* __restrict__ C, int M, int N, int K)
{
    __shared__ __align__(16) bf16 sA[BM * BK];   // [row][k], row stride 32
    __shared__ __align__(16) bf16 sB[BN * BK];

    const int tid  = threadIdx.x;
    const int lane = tid & 63;
    const int w    = tid >> 6;
    const int wm   = w >> 1;       // wave tile 64x64, 2x2 waves
    const int wn   = w & 1;
    const int m0   = blockIdx.x * BM;
    const int n0   = blockIdx.y * BN;
    const int col  = lane & 15;
    const int quad = lane >> 4;

    floatx4 acc[4][4] = {};

    for (int kt = 0; kt < K; kt += BK) {
        // Stage via registers: 512 chunks of 8 elems; chunk c -> row=c>>2,
        // kc=c&3. Thread t owns chunks t and t+256.
        bf16x8 ga[2], gb[2];
#pragma unroll
        for (int i = 0; i < 2; ++i) {
            const int c   = i * 256 + tid;
            const int row = c >> 2;
            const int kc  = c & 3;
            ga[i] = load8(&A[(size_t)(m0 + row) * K + kt + kc * 8]);
            gb[i] = load8(&W[(size_t)(n0 + row) * K + kt + kc * 8]);
        }
        __syncthreads();   // previous iteration's readers are done
#pragma unroll
        for (int i = 0; i < 2; ++i) {
            const int c = i * 256 + tid;
            *(bf16x8*)&sA[c * 8] = ga[i];
            *(bf16x8*)&sB[c * 8] = gb[i];
        }
        __syncthreads();   // tiles visible to all waves

        bf16x8 af[4], bfr[4];
#pragma unroll
        for (int mi = 0; mi < 4; ++mi)
            af[mi] = *(const bf16x8*)&sA[(wm * 64 + mi * 16 + col) * BK + quad * 8];
#pragma unroll
        for (int ni = 0; ni < 4; ++ni)
            bfr[ni] = *(const bf16x8*)&sB[(wn * 64 + ni * 16 + col) * BK + quad * 8];

#pragma unroll
        for (int mi = 0; mi < 4; ++mi)
#pragma unroll
            for (int ni = 0; ni < 4; ++ni)
                acc[mi][ni] = __builtin_amdgcn_mfma_f32_16x16x32_bf16(
                    af[mi], bfr[ni], acc[mi][ni], 0, 0, 0);
    }

    // Epilogue: C/D layout col = lane&15, row = quad*4 + r (per 16x16 tile).
#pragma unroll
    for (int mi = 0; mi < 4; ++mi) {
#pragma unroll
        for (int r = 0; r < 4; ++r) {
            const int row = m0 + wm * 64 + mi * 16 + quad * 4 + r;
#pragma unroll
            for (int ni = 0; ni < 4; ++ni) {
                const int cc = n0 + wn * 64 + ni * 16 + col;
                C[(size_t)row * N + cc] = (TC)acc[mi][ni][r];
            }
        }
    }
}

// Per-token head-mixing attention. One wave per token, 4 tokens per block.
// Q,K frags straight from global (K-contiguous, bf16). P: MFMA C-layout ->
// LDS -> A-layout (K zero-padded 16->32). V transposed into LDS as B-operand
// (g zero-padded 16->32 so pad contributes 0, never NaN).
// NOTE: o aliases q (in-place) -> no __restrict__ on q/o.
__global__ __launch_bounds__(256) void attn_heads(
    const bf16* q, const bf16* __restrict__ k,
    const bf16* __restrict__ v, bf16* o /* aliases q */)
{
    __shared__ __align__(16) bf16 sP[4][16 * 32];    // [wave][h][g(pad 32)]
    __shared__ __align__(16) bf16 sVt[4][64 * 32];   // [wave][d][g(pad 32)]

    const int tid   = threadIdx.x;
    const int lane  = tid & 63;
    const int w     = tid >> 6;
    const int token = blockIdx.x * 4 + w;
    const int col   = lane & 15;
    const int quad  = lane >> 4;

    const bf16* qt = q + (size_t)token * HIDDEN;
    const bf16* kt = k + (size_t)token * HIDDEN;
    const bf16* vt = v + (size_t)token * HIDDEN;

    // Zero the pad columns (g=16..31); data writes never touch them.
    for (int i = lane; i < 256; i += 64)             // sP pads: 16 rows x 16
        sP[w][(i >> 4) * 32 + 16 + (i & 15)] = (bf16)0.f;
    for (int i = lane; i < 1024; i += 64)            // sVt pads: 64 rows x 16
        sVt[w][(i >> 4) * 32 + 16 + (i & 15)] = (bf16)0.f;

    // S = Q K^T : A[m=h=lane&15][k=d=quad*8+j], B[n=g=lane&15][k=d], 2 chunks.
    bf16x8 qa0 = *(const bf16x8*)&qt[col * 64 + quad * 8];
    bf16x8 qa1 = *(const bf16x8*)&qt[col * 64 + 32 + quad * 8];
    bf16x8 kb0 = *(const bf16x8*)&kt[col * 64 + quad * 8];
    bf16x8 kb1 = *(const bf16x8*)&kt[col * 64 + 32 + quad * 8];
    floatx4 s = {};
    s = __builtin_amdgcn_mfma_f32_16x16x32_bf16(qa0, kb0, s, 0, 0, 0);
    s = __builtin_amdgcn_mfma_f32_16x16x32_bf16(qa1, kb1, s, 0, 0, 0);

    // Transpose V into sVt: read v[g=j][d=lane], write [d][g].
#pragma unroll
    for (int j = 0; j < 16; ++j)
        sVt[w][lane * 32 + j] = vt[j * 64 + lane];

    // Softmax over g. s[r] = S[h=quad*4+r][g=lane&15] * 1/sqrt(64).
    // 16 lanes sharing a quad hold one row's 16 cols; xor-reduce within 16.
#pragma unroll
    for (int r = 0; r < 4; ++r) {
        float x = s[r] * 0.125f;
        float m = x;
#pragma unroll
        for (int off = 1; off < 16; off <<= 1)
            m = fmaxf(m, __shfl_xor(m, off));
        float e = __expf(x - m);
        float su = e;
#pragma unroll
        for (int off = 1; off < 16; off <<= 1)
            su += __shfl_xor(su, off);
        sP[w][(quad * 4 + r) * 32 + col] = (bf16)(e / su);
    }

    __syncthreads();   // P + Vt visible

    // O = P V : A[m=h=lane&15][k=g=quad*8+j] from sP; 4 d-tiles of 16.
    bf16x8 pa = *(const bf16x8*)&sP[w][col * 32 + quad * 8];
#pragma unroll
    for (int dt = 0; dt < 4; ++dt) {
        bf16x8 vb = *(const bf16x8*)&sVt[w][(dt * 16 + col) * 32 + quad * 8];
        floatx4 o4 = {};
        o4 = __builtin_amdgcn_mfma_f32_16x16x32_bf16(pa, vb, o4, 0, 0, 0);
#pragma unroll
        for (int r = 0; r < 4; ++r)
            o[(size_t)token * HIDDEN + (quad * 4 + r) * 64 + dt * 16 + col] = (bf16)o4[r];
    }
}

extern "C" void kernel_launch(void* const* d_in, const int* in_sizes, int n_in,
                              void* d_out, int out_size, void* d_ws, size_t ws_size,
                              hipStream_t stream) {
    const float* x  = (const float*)d_in[0];
    const float* wq = (const float*)d_in[1];
    const float* wk = (const float*)d_in[2];
    const float* wv = (const float*)d_in[3];
    const float* wo = (const float*)d_in[4];
    float* out = (float*)d_out;

    const int M = in_sizes[0] / HIDDEN;   // 16384 tokens
    const int N = HIDDEN, K = HIDDEN;

    bf16* qb = (bf16*)d_ws;
    bf16* kb = qb + (size_t)M * HIDDEN;
    bf16* vb = kb + (size_t)M * HIDDEN;

    dim3 grid(M / BM, N / BN), block(256);
    gemm_bt<float, float, bf16><<<grid, block, 0, stream>>>(x, wq, qb, M, N, K);
    gemm_bt<float, float, bf16><<<grid, block, 0, stream>>>(x, wk, kb, M, N, K);
    gemm_bt<float, float, bf16><<<grid, block, 0, stream>>>(x, wv, vb, M, N, K);
    attn_heads<<<dim3(M / 4), block, 0, stream>>>(qb, kb, vb, qb);  // O in-place
    gemm_bt<bf16, float, float><<<grid, block, 0, stream>>>(qb, wo, out, M, N, K);
}

// Round 4
// 327.679 us; speedup vs baseline: 1.1905x; 1.1905x over previous
//
#include <hip/hip_runtime.h>
#include <hip/hip_bf16.h>

// Problem: B=4,S=4096 tokens (16384), HIDDEN=1024, 16 heads x 64 dim.
// "Attention" mixes HEADS per token (16x16 softmax over heads), not sequence.
// Inputs/output fp32; compute bf16-MFMA w/ fp32 accumulate (threshold is
// bf16-floor 4.5e-2; R3 passed at 1.6e-2).
//
// R3 -> R4: GEMMs were latency-bound (MfmaUtil 17%, VALUBusy 12%, HBM 20%).
//  (a) one-time fp32->bf16 conversion of X + packed weights -> all GEMMs use
//      global_load_lds width-16 async staging (m93->m97 = 517->874 TF step);
//  (b) QKV fused into one N=3072 GEMM, O written in-place -> Wo GEMM lda=3072;
//  (c) XOR swizzle (kc ^= (row>>1)&3) on LDS K-chunks -> 2-way (free) bank
//      access on b128 frag reads (was 8-way, 4.2M conflict cycles/dispatch);
//  (d) attn: no inter-wave barrier, vectorized Vt staging.
// Fallback to the proven R3 path if ws_size < 142.6 MB (host-constant branch).

typedef __bf16 bf16;
typedef __attribute__((ext_vector_type(8))) __bf16 bf16x8;
typedef __attribute__((ext_vector_type(4))) float floatx4;

#define HIDDEN 1024
#define BM 128
#define BN 128
#define BK 32

__device__ __forceinline__ void async_load16(const bf16* g, bf16* lds) {
    __builtin_amdgcn_global_load_lds(
        (const __attribute__((address_space(1))) void*)g,
        (__attribute__((address_space(3))) void*)lds, 16, 0, 0);
}

__device__ __forceinline__ bf16x8 load8(const bf16* p) {
    return *(const bf16x8*)p;
}
__device__ __forceinline__ bf16x8 load8(const float* p) {
    floatx4 lo = *(const floatx4*)p;
    floatx4 hi = *(const floatx4*)(p + 4);
    bf16x8 r;
#pragma unroll
    for (int i = 0; i < 4; ++i) { r[i] = (bf16)lo[i]; r[i + 4] = (bf16)hi[i]; }
    return r;
}

// ---------- fp32 -> bf16 conversion (one-time) ----------
__global__ __launch_bounds__(256) void cvt_f32_bf16(
    const float* __restrict__ src, bf16* __restrict__ dst, int n8)
{
    int i = blockIdx.x * 256 + threadIdx.x;
    if (i < n8) *(bf16x8*)&dst[(size_t)i * 8] = load8(&src[(size_t)i * 8]);
}

// Pack wq|wk|wv|wo (each 1024x1024 fp32) into one contiguous bf16 buffer.
__global__ __launch_bounds__(256) void cvt_w4(
    const float* __restrict__ wq, const float* __restrict__ wk,
    const float* __restrict__ wv, const float* __restrict__ wo,
    bf16* __restrict__ dst)
{
    const int per = (HIDDEN * HIDDEN) / 8;   // 131072 chunks per weight
    int i = blockIdx.x * 256 + threadIdx.x;  // < 4*per
    int wsel = i / per;                      // uniform per block (per%256==0)
    int off  = (i - wsel * per) * 8;
    const float* s = wsel == 0 ? wq : wsel == 1 ? wk : wsel == 2 ? wv : wo;
    *(bf16x8*)&dst[(size_t)i * 8] = load8(&s[off]);
}

// ---------- bf16 GEMM, async staging + swizzle (m97 structure) ----------
// C[m,n] = sum_k A[m,k]*W[n,k].  A row stride lda, W row stride K, C row
// stride ldc. LDS slot (row,kc') holds global chunk (row, kc'^((row>>1)&3)):
// b128 frag reads then hit each bank with exactly 2 lanes (free).
template <typename TC>
__global__ __launch_bounds__(256, 2) void gemm_async(
    const bf16* __restrict__ A, const bf16* __restrict__ W,
    TC* __restrict__ C, int M, int N, int K, int lda, int ldc)
{
    __shared__ __align__(16) bf16 sA[BM * BK];
    __shared__ __align__(16) bf16 sB[BN * BK];

    const int tid  = threadIdx.x;
    const int lane = tid & 63;
    const int w    = tid >> 6;
    const int wm   = w >> 1;
    const int wn   = w & 1;
    const int m0   = blockIdx.x * BM;
    const int n0   = blockIdx.y * BN;
    const int col  = lane & 15;
    const int quad = lane >> 4;
    // Swizzle selector for frag reads; (row>>1)&3 == (col>>1)&3 for all
    // 16-aligned row bases (disjoint bits, no carries).
    const int swz  = (quad ^ ((col >> 1) & 3)) * 8;

    floatx4 acc[4][4] = {};

    for (int kt = 0; kt < K; kt += BK) {
        // 512 16B chunks per matrix; wave w instr i covers slots [i*256+w*64, +64).
#pragma unroll
        for (int i = 0; i < 2; ++i) {
            const int c0  = i * 256 + w * 64;
            const int c   = c0 + lane;
            const int row = c >> 2;
            const int kc  = (c & 3) ^ ((row >> 1) & 3);   // swizzled source chunk
            async_load16(&A[(size_t)(m0 + row) * lda + kt + kc * 8], &sA[c0 * 8]);
            async_load16(&W[(size_t)(n0 + row) * K   + kt + kc * 8], &sB[c0 * 8]);
        }
        __syncthreads();   // compiler drains vmcnt before s_barrier

        bf16x8 af[4], bfr[4];
#pragma unroll
        for (int mi = 0; mi < 4; ++mi)
            af[mi] = *(const bf16x8*)&sA[(wm * 64 + mi * 16 + col) * BK + swz];
#pragma unroll
        for (int ni = 0; ni < 4; ++ni)
            bfr[ni] = *(const bf16x8*)&sB[(wn * 64 + ni * 16 + col) * BK + swz];

#pragma unroll
        for (int mi = 0; mi < 4; ++mi)
#pragma unroll
            for (int ni = 0; ni < 4; ++ni)
                acc[mi][ni] = __builtin_amdgcn_mfma_f32_16x16x32_bf16(
                    af[mi], bfr[ni], acc[mi][ni], 0, 0, 0);
        __syncthreads();   // protect LDS before next stage
    }

#pragma unroll
    for (int mi = 0; mi < 4; ++mi) {
#pragma unroll
        for (int r = 0; r < 4; ++r) {
            const int row = m0 + wm * 64 + mi * 16 + quad * 4 + r;
#pragma unroll
            for (int ni = 0; ni < 4; ++ni) {
                const int cc = n0 + wn * 64 + ni * 16 + col;
                C[(size_t)row * ldc + cc] = (TC)acc[mi][ni][r];
            }
        }
    }
}

// ---------- R3 fallback GEMM (fp32-or-bf16 in, register staging) ----------
template <typename TA, typename TB, typename TC>
__global__ __launch_bounds__(256, 2) void gemm_bt(
    const TA* __restrict__ A, const TB* __restrict__ W,
    TC* __restrict__ C, int M, int N, int K)
{
    __shared__ __align__(16) bf16 sA[BM * BK];
    __shared__ __align__(16) bf16 sB[BN * BK];

    const int tid  = threadIdx.x;
    const int lane = tid & 63;
    const int w    = tid >> 6;
    const int wm   = w >> 1;
    const int wn   = w & 1;
    const int m0   = blockIdx.x * BM;
    const int n0   = blockIdx.y * BN;
    const int col  = lane & 15;
    const int quad = lane >> 4;

    floatx4 acc[4][4] = {};

    for (int kt = 0; kt < K; kt += BK) {
        bf16x8 ga[2], gb[2];
#pragma unroll
        for (int i = 0; i < 2; ++i) {
            const int c   = i * 256 + tid;
            const int row = c >> 2;
            const int kc  = c & 3;
            ga[i] = load8(&A[(size_t)(m0 + row) * K + kt + kc * 8]);
            gb[i] = load8(&W[(size_t)(n0 + row) * K + kt + kc * 8]);
        }
        __syncthreads();
#pragma unroll
        for (int i = 0; i < 2; ++i) {
            const int c = i * 256 + tid;
            *(bf16x8*)&sA[c * 8] = ga[i];
            *(bf16x8*)&sB[c * 8] = gb[i];
        }
        __syncthreads();

        bf16x8 af[4], bfr[4];
#pragma unroll
        for (int mi = 0; mi < 4; ++mi)
            af[mi] = *(const bf16x8*)&sA[(wm * 64 + mi * 16 + col) * BK + quad * 8];
#pragma unroll
        for (int ni = 0; ni < 4; ++ni)
            bfr[ni] = *(const bf16x8*)&sB[(wn * 64 + ni * 16 + col) * BK + quad * 8];

#pragma unroll
        for (int mi = 0; mi < 4; ++mi)
#pragma unroll
            for (int ni = 0; ni < 4; ++ni)
                acc[mi][ni] = __builtin_amdgcn_mfma_f32_16x16x32_bf16(
                    af[mi], bfr[ni], acc[mi][ni], 0, 0, 0);
    }

#pragma unroll
    for (int mi = 0; mi < 4; ++mi) {
#pragma unroll
        for (int r = 0; r < 4; ++r) {
            const int row = m0 + wm * 64 + mi * 16 + quad * 4 + r;
#pragma unroll
            for (int ni = 0; ni < 4; ++ni) {
                const int cc = n0 + wn * 64 + ni * 16 + col;
                C[(size_t)row * N + cc] = (TC)acc[mi][ni][r];
            }
        }
    }
}

// ---------- per-token head-mixing attention ----------
// One wave per token; all LDS traffic wave-private (no barrier).
// qt = base + token*stride; kt = qt + koff; vt = qt + voff; O -> qt (in-place).
__global__ __launch_bounds__(256) void attn_heads(
    bf16* base, size_t koff, size_t voff, int stride)
{
    __shared__ __align__(16) bf16 sP[4][16 * 32];    // [wave][h][g pad->32]
    __shared__ __align__(16) bf16 sVt[4][64 * 40];   // [wave][d][g pad->32, row 40]

    const int tid   = threadIdx.x;
    const int lane  = tid & 63;
    const int w     = tid >> 6;
    const int token = blockIdx.x * 4 + w;
    const int col   = lane & 15;
    const int quad  = lane >> 4;

    bf16* qt = base + (size_t)token * stride;
    const bf16* kt = qt + koff;
    const bf16* vt = qt + voff;

    // Zero K-pad (g=16..31). sVt rows 40 elems (80B, 16B aligned).
    const bf16x8 z = {};
    *(bf16x8*)&sVt[w][lane * 40 + 16] = z;
    *(bf16x8*)&sVt[w][lane * 40 + 24] = z;
    if (lane < 16) {
        *(bf16x8*)&sP[w][lane * 32 + 16] = z;
        *(bf16x8*)&sP[w][lane * 32 + 24] = z;
    }

    // S = Q K^T : A[m=h][k=d], B[n=g][k=d], two K=32 chunks.
    bf16x8 qa0 = *(const bf16x8*)&qt[col * 64 + quad * 8];
    bf16x8 qa1 = *(const bf16x8*)&qt[col * 64 + 32 + quad * 8];
    bf16x8 kb0 = *(const bf16x8*)&kt[col * 64 + quad * 8];
    bf16x8 kb1 = *(const bf16x8*)&kt[col * 64 + 32 + quad * 8];
    floatx4 s = {};
    s = __builtin_amdgcn_mfma_f32_16x16x32_bf16(qa0, kb0, s, 0, 0, 0);
    s = __builtin_amdgcn_mfma_f32_16x16x32_bf16(qa1, kb1, s, 0, 0, 0);

    // Transpose V: lane gathers column d=lane (coalesced reads), writes one
    // contiguous 32B row of sVt as 2x b128.
    bf16x8 vc0, vc1;
#pragma unroll
    for (int j = 0; j < 8; ++j)  vc0[j] = vt[j * 64 + lane];
#pragma unroll
    for (int j = 0; j < 8; ++j)  vc1[j] = vt[(j + 8) * 64 + lane];
    *(bf16x8*)&sVt[w][lane * 40]     = vc0;
    *(bf16x8*)&sVt[w][lane * 40 + 8] = vc1;

    // Softmax over g (16 lanes of a quad hold one row).
#pragma unroll
    for (int r = 0; r < 4; ++r) {
        float x = s[r] * 0.125f;
        float m = x;
#pragma unroll
        for (int off = 1; off < 16; off <<= 1)
            m = fmaxf(m, __shfl_xor(m, off));
        float e = __expf(x - m);
        float su = e;
#pragma unroll
        for (int off = 1; off < 16; off <<= 1)
            su += __shfl_xor(su, off);
        sP[w][(quad * 4 + r) * 32 + col] = (bf16)(e / su);
    }

    // O = P V (wave-private LDS; compiler orders ds ops via lgkmcnt).
    bf16x8 pa = *(const bf16x8*)&sP[w][col * 32 + quad * 8];
#pragma unroll
    for (int dt = 0; dt < 4; ++dt) {
        bf16x8 vb = *(const bf16x8*)&sVt[w][(dt * 16 + col) * 40 + quad * 8];
        floatx4 o4 = {};
        o4 = __builtin_amdgcn_mfma_f32_16x16x32_bf16(pa, vb, o4, 0, 0, 0);
#pragma unroll
        for (int r = 0; r < 4; ++r)
            qt[(quad * 4 + r) * 64 + dt * 16 + col] = (bf16)o4[r];
    }
}

extern "C" void kernel_launch(void* const* d_in, const int* in_sizes, int n_in,
                              void* d_out, int out_size, void* d_ws, size_t ws_size,
                              hipStream_t stream) {
    const float* x  = (const float*)d_in[0];
    const float* wq = (const float*)d_in[1];
    const float* wk = (const float*)d_in[2];
    const float* wv = (const float*)d_in[3];
    const float* wo = (const float*)d_in[4];
    float* out = (float*)d_out;

    const int M = in_sizes[0] / HIDDEN;   // 16384 tokens
    const size_t MH = (size_t)M * HIDDEN;
    const size_t WH = (size_t)HIDDEN * HIDDEN;

    const size_t need = (MH + 4 * WH + (size_t)M * 3 * HIDDEN) * sizeof(bf16);

    if (ws_size >= need) {
        // Fast path: convert once, async-staged bf16 GEMMs.
        bf16* xb  = (bf16*)d_ws;          // [M][1024]
        bf16* wpk = xb + MH;              // [4][1024][1024] packed q|k|v|o
        bf16* qkv = wpk + 4 * WH;         // [M][3072], O overwrites q cols

        cvt_f32_bf16<<<dim3((int)(MH / 8 / 256)), 256, 0, stream>>>(x, xb, (int)(MH / 8));
        cvt_w4<<<dim3(2048), 256, 0, stream>>>(wq, wk, wv, wo, wpk);

        gemm_async<bf16><<<dim3(M / BM, 3 * HIDDEN / BN), 256, 0, stream>>>(
            xb, wpk, qkv, M, 3 * HIDDEN, HIDDEN, HIDDEN, 3 * HIDDEN);

        attn_heads<<<dim3(M / 4), 256, 0, stream>>>(qkv, 1024, 2048, 3 * HIDDEN);

        gemm_async<float><<<dim3(M / BM, HIDDEN / BN), 256, 0, stream>>>(
            qkv, wpk + 3 * WH, out, M, HIDDEN, HIDDEN, 3 * HIDDEN, HIDDEN);
    } else {
        // R3 proven fallback (needs 100.7 MB).
        bf16* qb = (bf16*)d_ws;
        bf16* kb = qb + MH;
        bf16* vb = kb + MH;
        dim3 grid(M / BM, HIDDEN / BN), block(256);
        gemm_bt<float, float, bf16><<<grid, block, 0, stream>>>(x, wq, qb, M, HIDDEN, HIDDEN);
        gemm_bt<float, float, bf16><<<grid, block, 0, stream>>>(x, wk, kb, M, HIDDEN, HIDDEN);
        gemm_bt<float, float, bf16><<<grid, block, 0, stream>>>(x, wv, vb, M, HIDDEN, HIDDEN);
        attn_heads<<<dim3(M / 4), block, 0, stream>>>(qb, MH, 2 * MH, HIDDEN);
        gemm_bt<bf16, float, float><<<grid, block, 0, stream>>>(qb, wo, out, M, HIDDEN, HIDDEN);
    }
}

// Round 5
// 315.238 us; speedup vs baseline: 1.2375x; 1.0395x over previous
//
#include <hip/hip_runtime.h>
#include <hip/hip_bf16.h>

// Problem: B=4,S=4096 tokens (16384), HIDDEN=1024, 16 heads x 64 dim.
// "Attention" mixes HEADS per token (16x16 softmax over heads), not sequence.
// Inputs/output fp32; compute bf16-MFMA w/ fp32 accumulate (threshold is
// bf16-floor 4.5e-2; R3/R4 passed at 1.6e-2).
//
// R4 -> R5 (R4: 327.7us; QKV gemm 132us/781TF at the m97 plateau, conflicts 0):
//  (a) attn sP pad 32->40: the pa b128 read was 8-way bank-conflicted
//      (row stride 16 dwords -> col*16%32 in {0,16}); pad 40 -> col*20%32
//      spreads 2-way (free, m136).
//  (b) attn writes O into xb (dead after QKV gemm) -> Wo GEMM reads a dense
//      lda=1024 A instead of stride-3072 rows of qkv. No extra workspace.
//  (c) cvt_x + cvt_w4 merged into one cvt_all launch.
// GEMM kernels intentionally untouched (QKV row is the visible counter ref).

typedef __bf16 bf16;
typedef __attribute__((ext_vector_type(8))) __bf16 bf16x8;
typedef __attribute__((ext_vector_type(4))) float floatx4;

#define HIDDEN 1024
#define BM 128
#define BN 128
#define BK 32

__device__ __forceinline__ void async_load16(const bf16* g, bf16* lds) {
    __builtin_amdgcn_global_load_lds(
        (const __attribute__((address_space(1))) void*)g,
        (__attribute__((address_space(3))) void*)lds, 16, 0, 0);
}

__device__ __forceinline__ bf16x8 load8(const bf16* p) {
    return *(const bf16x8*)p;
}
__device__ __forceinline__ bf16x8 load8(const float* p) {
    floatx4 lo = *(const floatx4*)p;
    floatx4 hi = *(const floatx4*)(p + 4);
    bf16x8 r;
#pragma unroll
    for (int i = 0; i < 4; ++i) { r[i] = (bf16)lo[i]; r[i + 4] = (bf16)hi[i]; }
    return r;
}

// ---------- one-time fp32 -> bf16 conversion: x then packed wq|wk|wv|wo ----
// Chunk i (8 elems): i < MH/8 -> xb; else weight region. All region sizes
// are multiples of 256 chunks -> source select is block-uniform.
__global__ __launch_bounds__(256) void cvt_all(
    const float* __restrict__ x,
    const float* __restrict__ wq, const float* __restrict__ wk,
    const float* __restrict__ wv, const float* __restrict__ wo,
    bf16* __restrict__ xb, bf16* __restrict__ wpk, int mh8)
{
    const int per = (HIDDEN * HIDDEN) / 8;   // 131072 chunks per weight
    int i = blockIdx.x * 256 + threadIdx.x;
    if (i < mh8) {
        *(bf16x8*)&xb[(size_t)i * 8] = load8(&x[(size_t)i * 8]);
    } else {
        int j = i - mh8;
        int wsel = j / per;
        int off  = (j - wsel * per) * 8;
        const float* s = wsel == 0 ? wq : wsel == 1 ? wk : wsel == 2 ? wv : wo;
        *(bf16x8*)&wpk[(size_t)j * 8] = load8(&s[off]);
    }
}

// ---------- bf16 GEMM, async staging + XOR swizzle (m97 structure) ----------
// C[m,n] = sum_k A[m,k]*W[n,k].  A row stride lda, W row stride K, C row
// stride ldc. LDS slot (row,kc') holds global chunk (row, kc'^((row>>1)&3)):
// b128 frag reads hit each bank with exactly 2 lanes (free).
template <typename TC>
__global__ __launch_bounds__(256, 2) void gemm_async(
    const bf16* __restrict__ A, const bf16* __restrict__ W,
    TC* __restrict__ C, int M, int N, int K, int lda, int ldc)
{
    __shared__ __align__(16) bf16 sA[BM * BK];
    __shared__ __align__(16) bf16 sB[BN * BK];

    const int tid  = threadIdx.x;
    const int lane = tid & 63;
    const int w    = tid >> 6;
    const int wm   = w >> 1;
    const int wn   = w & 1;
    const int m0   = blockIdx.x * BM;
    const int n0   = blockIdx.y * BN;
    const int col  = lane & 15;
    const int quad = lane >> 4;
    const int swz  = (quad ^ ((col >> 1) & 3)) * 8;

    floatx4 acc[4][4] = {};

    for (int kt = 0; kt < K; kt += BK) {
#pragma unroll
        for (int i = 0; i < 2; ++i) {
            const int c0  = i * 256 + w * 64;
            const int c   = c0 + lane;
            const int row = c >> 2;
            const int kc  = (c & 3) ^ ((row >> 1) & 3);
            async_load16(&A[(size_t)(m0 + row) * lda + kt + kc * 8], &sA[c0 * 8]);
            async_load16(&W[(size_t)(n0 + row) * K   + kt + kc * 8], &sB[c0 * 8]);
        }
        __syncthreads();

        bf16x8 af[4], bfr[4];
#pragma unroll
        for (int mi = 0; mi < 4; ++mi)
            af[mi] = *(const bf16x8*)&sA[(wm * 64 + mi * 16 + col) * BK + swz];
#pragma unroll
        for (int ni = 0; ni < 4; ++ni)
            bfr[ni] = *(const bf16x8*)&sB[(wn * 64 + ni * 16 + col) * BK + swz];

#pragma unroll
        for (int mi = 0; mi < 4; ++mi)
#pragma unroll
            for (int ni = 0; ni < 4; ++ni)
                acc[mi][ni] = __builtin_amdgcn_mfma_f32_16x16x32_bf16(
                    af[mi], bfr[ni], acc[mi][ni], 0, 0, 0);
        __syncthreads();
    }

#pragma unroll
    for (int mi = 0; mi < 4; ++mi) {
#pragma unroll
        for (int r = 0; r < 4; ++r) {
            const int row = m0 + wm * 64 + mi * 16 + quad * 4 + r;
#pragma unroll
            for (int ni = 0; ni < 4; ++ni) {
                const int cc = n0 + wn * 64 + ni * 16 + col;
                C[(size_t)row * ldc + cc] = (TC)acc[mi][ni][r];
            }
        }
    }
}

// ---------- R3 fallback GEMM (fp32-or-bf16 in, register staging) ----------
template <typename TA, typename TB, typename TC>
__global__ __launch_bounds__(256, 2) void gemm_bt(
    const TA* __restrict__ A, const TB* __restrict__ W,
    TC* __restrict__ C, int M, int N, int K)
{
    __shared__ __align__(16) bf16 sA[BM * BK];
    __shared__ __align__(16) bf16 sB[BN * BK];

    const int tid  = threadIdx.x;
    const int lane = tid & 63;
    const int w    = tid >> 6;
    const int wm   = w >> 1;
    const int wn   = w & 1;
    const int m0   = blockIdx.x * BM;
    const int n0   = blockIdx.y * BN;
    const int col  = lane & 15;
    const int quad = lane >> 4;

    floatx4 acc[4][4] = {};

    for (int kt = 0; kt < K; kt += BK) {
        bf16x8 ga[2], gb[2];
#pragma unroll
        for (int i = 0; i < 2; ++i) {
            const int c   = i * 256 + tid;
            const int row = c >> 2;
            const int kc  = c & 3;
            ga[i] = load8(&A[(size_t)(m0 + row) * K + kt + kc * 8]);
            gb[i] = load8(&W[(size_t)(n0 + row) * K + kt + kc * 8]);
        }
        __syncthreads();
#pragma unroll
        for (int i = 0; i < 2; ++i) {
            const int c = i * 256 + tid;
            *(bf16x8*)&sA[c * 8] = ga[i];
            *(bf16x8*)&sB[c * 8] = gb[i];
        }
        __syncthreads();

        bf16x8 af[4], bfr[4];
#pragma unroll
        for (int mi = 0; mi < 4; ++mi)
            af[mi] = *(const bf16x8*)&sA[(wm * 64 + mi * 16 + col) * BK + quad * 8];
#pragma unroll
        for (int ni = 0; ni < 4; ++ni)
            bfr[ni] = *(const bf16x8*)&sB[(wn * 64 + ni * 16 + col) * BK + quad * 8];

#pragma unroll
        for (int mi = 0; mi < 4; ++mi)
#pragma unroll
            for (int ni = 0; ni < 4; ++ni)
                acc[mi][ni] = __builtin_amdgcn_mfma_f32_16x16x32_bf16(
                    af[mi], bfr[ni], acc[mi][ni], 0, 0, 0);
    }

#pragma unroll
    for (int mi = 0; mi < 4; ++mi) {
#pragma unroll
        for (int r = 0; r < 4; ++r) {
            const int row = m0 + wm * 64 + mi * 16 + quad * 4 + r;
#pragma unroll
            for (int ni = 0; ni < 4; ++ni) {
                const int cc = n0 + wn * 64 + ni * 16 + col;
                C[(size_t)row * N + cc] = (TC)acc[mi][ni][r];
            }
        }
    }
}

// ---------- per-token head-mixing attention ----------
// One wave per token; all LDS traffic wave-private (no barrier).
// qt = base + token*stride; kt = qt + koff; vt = qt + voff.
// O -> ob + token*1024 (dense; ob may alias the q region in fallback mode —
// stores are data-dependent on the q loads, so no hazard).
__global__ __launch_bounds__(256) void attn_heads(
    bf16* base, size_t koff, size_t voff, int stride, bf16* ob)
{
    __shared__ __align__(16) bf16 sP[4][16 * 40];    // [wave][h][g pad->32, row 40]
    __shared__ __align__(16) bf16 sVt[4][64 * 40];   // [wave][d][g pad->32, row 40]

    const int tid   = threadIdx.x;
    const int lane  = tid & 63;
    const int w     = tid >> 6;
    const int token = blockIdx.x * 4 + w;
    const int col   = lane & 15;
    const int quad  = lane >> 4;

    bf16* qt = base + (size_t)token * stride;
    const bf16* kt = qt + koff;
    const bf16* vt = qt + voff;
    bf16* ot = ob + (size_t)token * HIDDEN;

    // Zero K-pad (g=16..31). Rows are 40 elems (80B, 16B aligned).
    const bf16x8 z = {};
    *(bf16x8*)&sVt[w][lane * 40 + 16] = z;
    *(bf16x8*)&sVt[w][lane * 40 + 24] = z;
    if (lane < 16) {
        *(bf16x8*)&sP[w][lane * 40 + 16] = z;
        *(bf16x8*)&sP[w][lane * 40 + 24] = z;
    }

    // S = Q K^T : A[m=h][k=d], B[n=g][k=d], two K=32 chunks.
    bf16x8 qa0 = *(const bf16x8*)&qt[col * 64 + quad * 8];
    bf16x8 qa1 = *(const bf16x8*)&qt[col * 64 + 32 + quad * 8];
    bf16x8 kb0 = *(const bf16x8*)&kt[col * 64 + quad * 8];
    bf16x8 kb1 = *(const bf16x8*)&kt[col * 64 + 32 + quad * 8];
    floatx4 s = {};
    s = __builtin_amdgcn_mfma_f32_16x16x32_bf16(qa0, kb0, s, 0, 0, 0);
    s = __builtin_amdgcn_mfma_f32_16x16x32_bf16(qa1, kb1, s, 0, 0, 0);

    // Transpose V: lane gathers column d=lane (coalesced 128B reads), writes
    // one contiguous 32B row of sVt as 2x b128.
    bf16x8 vc0, vc1;
#pragma unroll
    for (int j = 0; j < 8; ++j)  vc0[j] = vt[j * 64 + lane];
#pragma unroll
    for (int j = 0; j < 8; ++j)  vc1[j] = vt[(j + 8) * 64 + lane];
    *(bf16x8*)&sVt[w][lane * 40]     = vc0;
    *(bf16x8*)&sVt[w][lane * 40 + 8] = vc1;

    // Softmax over g (16 lanes of a quad hold one row).
#pragma unroll
    for (int r = 0; r < 4; ++r) {
        float x = s[r] * 0.125f;
        float m = x;
#pragma unroll
        for (int off = 1; off < 16; off <<= 1)
            m = fmaxf(m, __shfl_xor(m, off));
        float e = __expf(x - m);
        float su = e;
#pragma unroll
        for (int off = 1; off < 16; off <<= 1)
            su += __shfl_xor(su, off);
        sP[w][(quad * 4 + r) * 40 + col] = (bf16)(e / su);
    }

    // O = P V (wave-private LDS; compiler orders ds ops via lgkmcnt).
    bf16x8 pa = *(const bf16x8*)&sP[w][col * 40 + quad * 8];
#pragma unroll
    for (int dt = 0; dt < 4; ++dt) {
        bf16x8 vb = *(const bf16x8*)&sVt[w][(dt * 16 + col) * 40 + quad * 8];
        floatx4 o4 = {};
        o4 = __builtin_amdgcn_mfma_f32_16x16x32_bf16(pa, vb, o4, 0, 0, 0);
#pragma unroll
        for (int r = 0; r < 4; ++r)
            ot[(quad * 4 + r) * 64 + dt * 16 + col] = (bf16)o4[r];
    }
}

extern "C" void kernel_launch(void* const* d_in, const int* in_sizes, int n_in,
                              void* d_out, int out_size, void* d_ws, size_t ws_size,
                              hipStream_t stream) {
    const float* x  = (const float*)d_in[0];
    const float* wq = (const float*)d_in[1];
    const float* wk = (const float*)d_in[2];
    const float* wv = (const float*)d_in[3];
    const float* wo = (const float*)d_in[4];
    float* out = (float*)d_out;

    const int M = in_sizes[0] / HIDDEN;   // 16384 tokens
    const size_t MH = (size_t)M * HIDDEN;
    const size_t WH = (size_t)HIDDEN * HIDDEN;

    const size_t need = (MH + 4 * WH + (size_t)M * 3 * HIDDEN) * sizeof(bf16);

    if (ws_size >= need) {
        // Fast path: convert once, async-staged bf16 GEMMs.
        bf16* xb  = (bf16*)d_ws;          // [M][1024]; reused as O after QKV
        bf16* wpk = xb + MH;              // [4][1024][1024] packed q|k|v|o
        bf16* qkv = wpk + 4 * WH;         // [M][3072]

        const int mh8 = (int)(MH / 8);
        const int nchunks = mh8 + (int)(4 * WH / 8);
        cvt_all<<<dim3(nchunks / 256), 256, 0, stream>>>(x, wq, wk, wv, wo,
                                                         xb, wpk, mh8);

        gemm_async<bf16><<<dim3(M / BM, 3 * HIDDEN / BN), 256, 0, stream>>>(
            xb, wpk, qkv, M, 3 * HIDDEN, HIDDEN, HIDDEN, 3 * HIDDEN);

        // xb is dead now; attn writes O into it (dense lda=1024 for Wo GEMM).
        attn_heads<<<dim3(M / 4), 256, 0, stream>>>(qkv, 1024, 2048,
                                                    3 * HIDDEN, xb);

        gemm_async<float><<<dim3(M / BM, HIDDEN / BN), 256, 0, stream>>>(
            xb, wpk + 3 * WH, out, M, HIDDEN, HIDDEN, HIDDEN, HIDDEN);
    } else {
        // R3 proven fallback (needs 100.7 MB).
        bf16* qb = (bf16*)d_ws;
        bf16* kb = qb + MH;
        bf16* vb = kb + MH;
        dim3 grid(M / BM, HIDDEN / BN), block(256);
        gemm_bt<float, float, bf16><<<grid, block, 0, stream>>>(x, wq, qb, M, HIDDEN, HIDDEN);
        gemm_bt<float, float, bf16><<<grid, block, 0, stream>>>(x, wk, kb, M, HIDDEN, HIDDEN);
        gemm_bt<float, float, bf16><<<grid, block, 0, stream>>>(x, wv, vb, M, HIDDEN, HIDDEN);
        attn_heads<<<dim3(M / 4), block, 0, stream>>>(qb, MH, 2 * MH, HIDDEN, qb);
        gemm_bt<bf16, float, float><<<grid, block, 0, stream>>>(qb, wo, out, M, HIDDEN, HIDDEN);
    }
}